// Round 1
// baseline (256.635 us; speedup 1.0000x reference)
//
#include <hip/hip_runtime.h>

// 2 points per thread; all global loads for both points issued before any
// arithmetic (breaks the 28-VGPR load-serialization of v1 -> 2x MLP/wave).
// LDS-staged transpose -> contiguous float4 output stores (proven 0-conflict).
#define PTS 512   // points per block (256 threads x 2)

__device__ __forceinline__ void compute_row(
    float4 q, float m, float2 sc, float p0, float p1, float p2,
    float4 vm0, float4 vm1, float4 vm2, float4 vm3, float* __restrict__ o)
{
    float r = q.x, x = q.y, y = q.z, z = q.w;
    float s0 = m * sc.x;
    float s1 = m * sc.y;

    float R00 = 1.0f - 2.0f * (y * y + z * z);
    float R10 = 2.0f * (x * y + r * z);
    float R20 = 2.0f * (x * z - r * y);
    float R01 = 2.0f * (x * y - r * z);
    float R11 = 1.0f - 2.0f * (x * x + z * z);
    float R21 = 2.0f * (y * z + r * x);

    float u0 = s0 * R00, u1 = s0 * R10, u2 = s0 * R20;
    float v0 = s1 * R01, v1 = s1 * R11, v2 = s1 * R21;

    o[0] = vm0.x * u0 + vm1.x * u1 + vm2.x * u2;
    o[1] = vm0.x * v0 + vm1.x * v1 + vm2.x * v2;
    o[2] = vm0.x * p0 + vm1.x * p1 + vm2.x * p2 + vm3.x;
    o[3] = vm0.y * u0 + vm1.y * u1 + vm2.y * u2;
    o[4] = vm0.y * v0 + vm1.y * v1 + vm2.y * v2;
    o[5] = vm0.y * p0 + vm1.y * p1 + vm2.y * p2 + vm3.y;
    o[6] = vm0.z * u0 + vm1.z * u1 + vm2.z * u2;
    o[7] = vm0.z * v0 + vm1.z * v1 + vm2.z * v2;
    o[8] = vm0.z * p0 + vm1.z * p1 + vm2.z * p2 + vm3.z;
}

__global__ __launch_bounds__(256) void cov_proj_kernel(
    const float4* __restrict__ rot,     // (N,4) as float4
    const float*  __restrict__ mod,     // (1,)
    const float2* __restrict__ scale,   // (N,2) as float2
    const float*  __restrict__ p_k,     // (N,3)
    const float4* __restrict__ vm,      // (N,16) as 4x float4 per row
    float*        __restrict__ out,     // (N,9)
    int n)
{
    __shared__ __attribute__((aligned(16))) float lds_out[PTS * 9];  // 18 KiB

    const int t = threadIdx.x;
    const int base = blockIdx.x * PTS;
    const int i0 = base + t;
    const int i1 = base + t + 256;
    const float m = mod[0];

    if (base + PTS <= n) {
        // ---- Full block fast path: issue ALL loads for both points first ----
        float4 qA = rot[i0];
        float4 qB = rot[i1];
        float2 scA = scale[i0];
        float2 scB = scale[i1];
        float pA0 = p_k[3 * i0 + 0];
        float pA1 = p_k[3 * i0 + 1];
        float pA2 = p_k[3 * i0 + 2];
        float pB0 = p_k[3 * i1 + 0];
        float pB1 = p_k[3 * i1 + 1];
        float pB2 = p_k[3 * i1 + 2];
        float4 a0 = vm[4 * i0 + 0];
        float4 a1 = vm[4 * i0 + 1];
        float4 a2 = vm[4 * i0 + 2];
        float4 a3 = vm[4 * i0 + 3];
        float4 b0 = vm[4 * i1 + 0];
        float4 b1 = vm[4 * i1 + 1];
        float4 b2 = vm[4 * i1 + 2];
        float4 b3 = vm[4 * i1 + 3];

        compute_row(qA, m, scA, pA0, pA1, pA2, a0, a1, a2, a3,
                    &lds_out[9 * t]);
        compute_row(qB, m, scB, pB0, pB1, pB2, b0, b1, b2, b3,
                    &lds_out[9 * (t + 256)]);
    } else {
        // ---- Tail block: per-point guards, scalar path ----
        if (i0 < n) {
            float4 q = rot[i0];
            float2 sc = scale[i0];
            float p0 = p_k[3 * i0 + 0], p1 = p_k[3 * i0 + 1], p2 = p_k[3 * i0 + 2];
            float4 v0 = vm[4 * i0 + 0], v1 = vm[4 * i0 + 1];
            float4 v2 = vm[4 * i0 + 2], v3 = vm[4 * i0 + 3];
            compute_row(q, m, sc, p0, p1, p2, v0, v1, v2, v3, &lds_out[9 * t]);
        }
        if (i1 < n) {
            float4 q = rot[i1];
            float2 sc = scale[i1];
            float p0 = p_k[3 * i1 + 0], p1 = p_k[3 * i1 + 1], p2 = p_k[3 * i1 + 2];
            float4 v0 = vm[4 * i1 + 0], v1 = vm[4 * i1 + 1];
            float4 v2 = vm[4 * i1 + 2], v3 = vm[4 * i1 + 3];
            compute_row(q, m, sc, p0, p1, p2, v0, v1, v2, v3,
                        &lds_out[9 * (t + 256)]);
        }
    }
    __syncthreads();

    const int points = min(PTS, n - base);
    const size_t out_base = (size_t)base * 9;

    if (points == PTS) {
        // Full block: 4608 floats = 1152 float4, contiguous & 16B-aligned
        // (out_base*4 = blockIdx*18432 bytes, 18432 % 16 == 0).
        const float4* lo4 = (const float4*)lds_out;
        float4* go4 = (float4*)(out + out_base);
        #pragma unroll
        for (int k = t; k < (PTS * 9) / 4; k += 256) go4[k] = lo4[k];
    } else {
        const int total = points * 9;
        for (int k = t; k < total; k += 256) out[out_base + k] = lds_out[k];
    }
}

extern "C" void kernel_launch(void* const* d_in, const int* in_sizes, int n_in,
                              void* d_out, int out_size, void* d_ws, size_t ws_size,
                              hipStream_t stream) {
    const float4* rot   = (const float4*)d_in[0];
    const float*  mod   = (const float*)d_in[1];
    const float2* scale = (const float2*)d_in[2];
    const float*  p_k   = (const float*)d_in[3];
    const float4* vm    = (const float4*)d_in[4];
    float* out = (float*)d_out;

    int n = in_sizes[0] / 4;  // rot has N*4 elements
    int block = 256;
    int grid = (n + PTS - 1) / PTS;
    cov_proj_kernel<<<grid, block, 0, stream>>>(rot, mod, scale, p_k, vm, out, n);
}

// Round 2
// 254.137 us; speedup vs baseline: 1.0098x; 1.0098x over previous
//
#include <hip/hip_runtime.h>

// v3: ALL global traffic as dense contiguous float4 streams (copy-ubench shape).
// vm (64% of input bytes) was read at 64B lane-stride -> 64 lines/instr, which
// saturates the per-CU outstanding-line budget at ~half streaming BW.
// Now: cooperative dense float4 loads -> LDS (pitch-20 rows, bank-uniform for
// b128 read+write) -> per-thread compute -> LDS -> dense float4 stores.
#define PTS 256
#define VM_PITCH 20  // 16 + 4 pad dwords: keeps b128 16B-aligned; 20*4=80B row
                     // stride => bank starts {0,4,..,28}*, uniform 8 accesses/bank
                     // per b128 wave-instr (minimum possible) on read AND write.

__device__ __forceinline__ void compute_row(
    float4 q, float m, float2 sc, float p0, float p1, float p2,
    float4 vm0, float4 vm1, float4 vm2, float4 vm3, float* __restrict__ o)
{
    float r = q.x, x = q.y, y = q.z, z = q.w;
    float s0 = m * sc.x;
    float s1 = m * sc.y;

    float R00 = 1.0f - 2.0f * (y * y + z * z);
    float R10 = 2.0f * (x * y + r * z);
    float R20 = 2.0f * (x * z - r * y);
    float R01 = 2.0f * (x * y - r * z);
    float R11 = 1.0f - 2.0f * (x * x + z * z);
    float R21 = 2.0f * (y * z + r * x);

    float u0 = s0 * R00, u1 = s0 * R10, u2 = s0 * R20;
    float v0 = s1 * R01, v1 = s1 * R11, v2 = s1 * R21;

    o[0] = vm0.x * u0 + vm1.x * u1 + vm2.x * u2;
    o[1] = vm0.x * v0 + vm1.x * v1 + vm2.x * v2;
    o[2] = vm0.x * p0 + vm1.x * p1 + vm2.x * p2 + vm3.x;
    o[3] = vm0.y * u0 + vm1.y * u1 + vm2.y * u2;
    o[4] = vm0.y * v0 + vm1.y * v1 + vm2.y * v2;
    o[5] = vm0.y * p0 + vm1.y * p1 + vm2.y * p2 + vm3.y;
    o[6] = vm0.z * u0 + vm1.z * u1 + vm2.z * u2;
    o[7] = vm0.z * v0 + vm1.z * v1 + vm2.z * v2;
    o[8] = vm0.z * p0 + vm1.z * p1 + vm2.z * p2 + vm3.z;
}

__global__ __launch_bounds__(256) void cov_proj_kernel(
    const float4* __restrict__ rot,     // (N,4) as float4
    const float*  __restrict__ mod,     // (1,)
    const float2* __restrict__ scale,   // (N,2) as float2
    const float*  __restrict__ p_k,     // (N,3)
    const float4* __restrict__ vm,      // (N,16) as 4x float4 per row
    float*        __restrict__ out,     // (N,9)
    int n)
{
    __shared__ __attribute__((aligned(16))) float lds_vm[PTS * VM_PITCH]; // 20 KiB
    __shared__ __attribute__((aligned(16))) float lds_pk[PTS * 3];        // 3 KiB
    __shared__ __attribute__((aligned(16))) float lds_out[PTS * 9];       // 9 KiB

    const int t = threadIdx.x;
    const int base = blockIdx.x * PTS;
    const float m = mod[0];

    if (base + PTS <= n) {
        // ---- dense cooperative staging: every load instr covers 1KB contig ----
        const float4* vm4 = vm + (size_t)base * 4;          // 1024 float4
        #pragma unroll
        for (int rr = 0; rr < 4; ++rr) {
            int j = rr * 256 + t;
            float4 v = vm4[j];
            int pt = j >> 2, k4 = j & 3;
            *(float4*)&lds_vm[pt * VM_PITCH + 4 * k4] = v;  // uniform banks
        }
        const float4* pk4 = (const float4*)(p_k + (size_t)base * 3);  // 192 float4
        if (t < 192) {
            float4 v = pk4[t];
            *(float4*)&lds_pk[4 * t] = v;                   // contiguous copy
        }
        // rot/scale are already dense at 16B/8B lane-stride: load direct.
        float4 q  = rot[base + t];
        float2 sc = scale[base + t];

        __syncthreads();

        float4 vm0 = *(const float4*)&lds_vm[t * VM_PITCH + 0];
        float4 vm1 = *(const float4*)&lds_vm[t * VM_PITCH + 4];
        float4 vm2 = *(const float4*)&lds_vm[t * VM_PITCH + 8];
        float4 vm3 = *(const float4*)&lds_vm[t * VM_PITCH + 12];
        float p0 = lds_pk[3 * t + 0];
        float p1 = lds_pk[3 * t + 1];
        float p2 = lds_pk[3 * t + 2];

        compute_row(q, m, sc, p0, p1, p2, vm0, vm1, vm2, vm3, &lds_out[9 * t]);
    } else {
        // ---- tail block (1 of 7813): direct guarded path ----
        const int i = base + t;
        if (i < n) {
            float4 q  = rot[i];
            float2 sc = scale[i];
            float p0 = p_k[3 * i + 0], p1 = p_k[3 * i + 1], p2 = p_k[3 * i + 2];
            float4 v0 = vm[4 * i + 0], v1 = vm[4 * i + 1];
            float4 v2 = vm[4 * i + 2], v3 = vm[4 * i + 3];
            compute_row(q, m, sc, p0, p1, p2, v0, v1, v2, v3, &lds_out[9 * t]);
        }
        __syncthreads();  // pair with the fast path's first barrier
    }
    __syncthreads();

    const int points = min(PTS, n - base);
    const size_t out_base = (size_t)base * 9;

    if (points == PTS) {
        // 2304 floats = 576 float4, contiguous & 16B-aligned
        // (out_base*4 = blockIdx*9216 bytes, 9216 % 16 == 0).
        const float4* lo4 = (const float4*)lds_out;
        float4* go4 = (float4*)(out + out_base);
        #pragma unroll
        for (int k = t; k < (PTS * 9) / 4; k += 256) go4[k] = lo4[k];
    } else {
        const int total = points * 9;
        for (int k = t; k < total; k += 256) out[out_base + k] = lds_out[k];
    }
}

extern "C" void kernel_launch(void* const* d_in, const int* in_sizes, int n_in,
                              void* d_out, int out_size, void* d_ws, size_t ws_size,
                              hipStream_t stream) {
    const float4* rot   = (const float4*)d_in[0];
    const float*  mod   = (const float*)d_in[1];
    const float2* scale = (const float2*)d_in[2];
    const float*  p_k   = (const float*)d_in[3];
    const float4* vm    = (const float4*)d_in[4];
    float* out = (float*)d_out;

    int n = in_sizes[0] / 4;  // rot has N*4 elements
    int block = 256;
    int grid = (n + PTS - 1) / PTS;
    cov_proj_kernel<<<grid, block, 0, stream>>>(rot, mod, scale, p_k, vm, out, n);
}